// Round 1
// baseline (250.521 us; speedup 1.0000x reference)
//
#include <hip/hip_runtime.h>

// LSS voxel pooling: B=2,N=6,D=48,FH=16,FW=44,C=80 -> out [2,80,1,256,256]
//
// R6 theory: R5's coalesced atomics into S were STILL the bottleneck --
// 2.03M per-lane float atomics with 16 lanes/64B-line serialize at the TCC
// atomic unit regardless of address contiguity (R5 flat vs R4 was the tell).
// Fix: no float atomics at all. Per-column-group sums -> plain float4 stores
// into compact P[entry][80] (8.1MB); one atomicExch per group (~25k) links
// entries onto per-voxel lists; gather kernel walks lists and writes out
// dense (replaces zero+transpose, and all of S's 126MB round trip).
//
// Numerics (verified R1-R5, absmax 0.016): f64 geometry seeded with bit-exact
// f32 frustum values + f32-valued bounds constants; trunc-toward-zero.
// Sum order: per-column h-ascending (unchanged), voxel-collision order now
// LIFO list instead of atomic arrival order (both nondeterministic-class).

#define NCH       80
#define GRID_HW   65536    // 256*256
#define OUT_PER_B 5242880  // 80*65536
#define HSTRIDE   3520     // 44*80 floats between h rows
#define PTS_PER_BN 33792   // 48*16*44

// workspace layout (bytes)
#define N_ENT_MAX 405504           // 576 slices * 704 pts worst case
#define P_BYTES   129761280u       // N_ENT_MAX * 80 * 4
#define NEXT_OFF  129761280u
#define HEAD_OFF  131383296u       // NEXT_OFF + 405504*4
#define CNT_OFF   131907584u       // HEAD_OFF + 131072*4
#define WS_NEED   131907588u

__device__ inline void inv3(const double a[9], double inv[9]) {
    double c00 =  a[4]*a[8] - a[5]*a[7];
    double c01 = -(a[3]*a[8] - a[5]*a[6]);
    double c02 =  a[3]*a[7] - a[4]*a[6];
    double det = a[0]*c00 + a[1]*c01 + a[2]*c02;
    double id  = 1.0/det;
    inv[0] = c00*id;
    inv[1] = (a[2]*a[7]-a[1]*a[8])*id;
    inv[2] = (a[1]*a[5]-a[2]*a[4])*id;
    inv[3] = c01*id;
    inv[4] = (a[0]*a[8]-a[2]*a[6])*id;
    inv[5] = (a[2]*a[3]-a[0]*a[5])*id;
    inv[6] = c02*id;
    inv[7] = (a[1]*a[6]-a[0]*a[7])*id;
    inv[8] = (a[0]*a[4]-a[1]*a[3])*id;
}

// o[0..8]=inv(post_rots), [9..17]=rots@inv(intrins), [18..20]=post_trans, [21..23]=trans
__device__ inline void prep_bn(const float* __restrict__ rots,
                               const float* __restrict__ trans,
                               const float* __restrict__ intrins,
                               const float* __restrict__ post_rots,
                               const float* __restrict__ post_trans,
                               int bn, double* o) {
    double pr[9], kk[9], rt[9], ipr[9], ik[9];
    #pragma unroll
    for (int i = 0; i < 9; i++) {
        pr[i] = (double)post_rots[bn*9 + i];
        kk[i] = (double)intrins[bn*9 + i];
        rt[i] = (double)rots[bn*9 + i];
    }
    inv3(pr, ipr);
    inv3(kk, ik);
    #pragma unroll
    for (int i = 0; i < 9; i++) o[i] = ipr[i];
    #pragma unroll
    for (int r = 0; r < 3; r++)
        #pragma unroll
        for (int c = 0; c < 3; c++)
            o[9 + r*3 + c] = rt[r*3+0]*ik[0*3+c] + rt[r*3+1]*ik[1*3+c] + rt[r*3+2]*ik[2*3+c];
    #pragma unroll
    for (int i = 0; i < 3; i++) o[18 + i] = (double)post_trans[bn*3 + i];
    #pragma unroll
    for (int i = 0; i < 3; i++) o[21 + i] = (double)trans[bn*3 + i];
}

// fallback-path prep kernel (writes tw[bn*24..])
__global__ void prep_kernel(const float* __restrict__ rots,
                            const float* __restrict__ trans,
                            const float* __restrict__ intrins,
                            const float* __restrict__ post_rots,
                            const float* __restrict__ post_trans,
                            double* __restrict__ tw) {
    int bn = threadIdx.x;
    if (bn >= 12) return;
    prep_bn(rots, trans, intrins, post_rots, post_trans, bn, tw + bn*24);
}

__global__ __launch_bounds__(256) void zero_kernel(float4* __restrict__ p, int n4) {
    int i = blockIdx.x * 256 + threadIdx.x;
    int stride = gridDim.x * 256;
    for (; i < n4; i += stride) p[i] = make_float4(0.f, 0.f, 0.f, 0.f);
}

__global__ __launch_bounds__(256) void init_heads(int* __restrict__ head, int* __restrict__ counter) {
    int i = blockIdx.x * 256 + threadIdx.x;
    if (i < 131072) head[i] = -1;
    if (i == 0) counter[0] = 0;
}

// ---- shared geometry: fills s_base (vox id = b*65536+gy*256+gx, or -1). ----
__device__ inline void geom_points(const double* __restrict__ t,
                                   int b, int d, int tid, int* s_base) {
    const float dsv = __fadd_rn(2.0f, __fmul_rn((float)(56.0 / 48.0), (float)d));
    for (int idx = tid; idx < 704; idx += 256) {
        const int h = idx / 44;
        const int w = idx - h * 44;
        float xsv = (w == 43) ? 703.0f : (float)((double)w * (703.0 / 43.0));
        float ysv = (float)(h * 17);

        double px = (double)xsv - t[18];
        double py = (double)ysv - t[19];
        double pz = (double)dsv - t[20];
        double q0 = t[0]*px + t[1]*py + t[2]*pz;
        double q1 = t[3]*px + t[4]*py + t[5]*pz;
        double q2 = t[6]*px + t[7]*py + t[8]*pz;
        q0 *= q2;
        q1 *= q2;
        double e0 = t[9]*q0  + t[10]*q1 + t[11]*q2 + t[21];
        double e1 = t[12]*q0 + t[13]*q1 + t[14]*q2 + t[22];
        double e2 = t[15]*q0 + t[16]*q1 + t[17]*q2 + t[23];

        const double lxy = (double)(-51.2f);
        const double dxy = (double)(0.4f);
        int gx = (int)((e0 - lxy) / dxy);
        int gy = (int)((e1 - lxy) / dxy);
        int gz = (int)((e2 - (double)(-10.0f)) / (double)(20.0f));
        int base = -1;
        if (gx >= 0 && gx < 256 && gy >= 0 && gy < 256 && gz == 0)
            base = (b << 16) | (gy << 8) | gx;     // voxel id (incl. batch)
        s_base[idx] = base;
    }
}

// Main path: per-column-group register sums -> plain stores into compact
// P[entry][80]; entry pushed onto per-voxel LIFO list (1 atomicExch/group).
__global__ __launch_bounds__(256) void scatter_compact(const float* __restrict__ x,
                                                       const float* __restrict__ rots,
                                                       const float* __restrict__ trans,
                                                       const float* __restrict__ intrins,
                                                       const float* __restrict__ post_rots,
                                                       const float* __restrict__ post_trans,
                                                       float* __restrict__ P,
                                                       int* __restrict__ nxt,
                                                       int* __restrict__ head,
                                                       int* __restrict__ counter) {
    __shared__ double   s_t[24];
    __shared__ int      s_base[704];
    __shared__ int      s_gbase[704];    // [w*16+k]
    __shared__ unsigned s_gmask[704];    // [w*16+k]
    __shared__ int      s_gcount[44];
    __shared__ int      s_goff[44];
    __shared__ short    s_gslot[704];    // flat group -> (w<<4)|k
    __shared__ int      s_eb, s_G;

    const int tid = threadIdx.x;
    const int bn  = blockIdx.x / 48;
    const int d   = blockIdx.x - bn * 48;
    const int b   = bn / 6;

    if (tid == 0)
        prep_bn(rots, trans, intrins, post_rots, post_trans, bn, s_t);
    __syncthreads();

    geom_points(s_t, b, d, tid, s_base);
    __syncthreads();

    // group the 16 h-rows of each column by voxel id (real data: 1 group/col)
    if (tid < 44) {
        int gb[16]; unsigned gm[16];
        int cnt = 0;
        #pragma unroll
        for (int h = 0; h < 16; h++) {
            int pb = s_base[h * 44 + tid];
            if (pb >= 0) {
                int j = 0;
                for (; j < cnt; j++) if (gb[j] == pb) break;
                if (j < cnt) gm[j] |= (1u << h);
                else { gb[cnt] = pb; gm[cnt] = (1u << h); cnt++; }
            }
        }
        s_gcount[tid] = cnt;
        for (int j = 0; j < cnt; j++) {
            s_gbase[tid * 16 + j] = gb[j];
            s_gmask[tid * 16 + j] = gm[j];
        }
    }
    __syncthreads();

    if (tid == 0) {
        int off = 0;
        for (int w = 0; w < 44; w++) { s_goff[w] = off; off += s_gcount[w]; }
        s_G  = off;
        s_eb = atomicAdd(counter, off);   // reserve contiguous entry range
    }
    __syncthreads();

    // link entries onto per-voxel lists; build flat-group -> slot map
    if (tid < 44) {
        int off = s_goff[tid];
        int cnt = s_gcount[tid];
        for (int k = 0; k < cnt; k++) {
            int g = off + k;
            s_gslot[g] = (short)((tid << 4) | k);
            int e = s_eb + g;
            nxt[e] = atomicExch(&head[s_gbase[tid * 16 + k]], e);
        }
    }
    __syncthreads();

    const int G  = s_G;
    const int eb = s_eb;
    const float* xb0 = x + ((size_t)bn * PTS_PER_BN + (size_t)d * 704) * NCH;
    // lanes: c4-minor, g-major -> P stores are 1KB-contiguous per wave
    for (int item = tid; item < G * 20; item += 256) {
        int g  = item / 20;
        int c4 = item - g * 20;
        int slot = (int)s_gslot[g];
        int w = slot >> 4;
        int k = slot & 15;
        unsigned mm = s_gmask[w * 16 + k];
        const float* xb = xb0 + (size_t)w * NCH + c4 * 4;
        float ax = 0.f, ay = 0.f, az = 0.f, aw = 0.f;
        #pragma unroll
        for (int h = 0; h < 16; h++) {
            if ((mm >> h) & 1u) {
                float4 v = *(const float4*)(xb + h * HSTRIDE);
                ax += v.x; ay += v.y; az += v.z; aw += v.w;
            }
        }
        float4 r; r.x = ax; r.y = ay; r.z = az; r.w = aw;
        *(float4*)(P + (size_t)(eb + g) * NCH + c4 * 4) = r;
    }
}

// Walk per-voxel lists, sum P rows, write out[b][c][v] dense (all of out).
__global__ __launch_bounds__(256) void gather_kernel(const float* __restrict__ P,
                                                     const int* __restrict__ nxt,
                                                     const int* __restrict__ head,
                                                     float* __restrict__ out) {
    __shared__ float tile[64 * 81];
    const int tid = threadIdx.x;
    const int b   = blockIdx.x >> 10;
    const int v0  = (blockIdx.x & 1023) * 64;
    const int* hb = head + (b << 16) + v0;
    #pragma unroll
    for (int i = 0; i < 20; i++) {
        int j = i * 256 + tid;          // 0..5119
        int v = j / 80;
        int c = j - v * 80;
        float s = 0.f;
        int e = hb[v];                  // same addr for the 80 lanes of v
        while (e >= 0) {
            s += P[(size_t)e * NCH + c];  // 320B contiguous per entry
            e = nxt[e];
        }
        tile[v * 81 + c] = s;
    }
    __syncthreads();
    float* dst = out + (size_t)b * OUT_PER_B + v0;
    #pragma unroll
    for (int i = 0; i < 20; i++) {
        int k  = i * 256 + tid;
        int c  = k >> 6;                // 0..79
        int lv = k & 63;
        dst[(size_t)c * GRID_HW + lv] = tile[lv * 81 + c];  // 256B/wave-row
    }
}

// Fallback (ws too small): direct atomics into out (R3 structure).
__global__ __launch_bounds__(256) void scatter_direct_kernel(const float* __restrict__ x,
                                                             const double* __restrict__ ws,
                                                             float* __restrict__ out) {
    __shared__ int      s_base[704];
    __shared__ int      s_colbase[44];
    __shared__ unsigned s_mask[44];
    __shared__ unsigned s_fb[44];

    const int tid = threadIdx.x;
    const int bn  = blockIdx.x / 48;
    const int d   = blockIdx.x - bn * 48;
    const int b   = bn / 6;
    geom_points(ws + bn * 24, b, d, tid, s_base);
    __syncthreads();

    if (tid < 44) {
        int cb = -1; unsigned mm = 0, fb = 0;
        #pragma unroll
        for (int h = 0; h < 16; h++) {
            int pb = s_base[h * 44 + tid];
            if (pb >= 0) {
                if (cb < 0) cb = pb;
                if (pb == cb) mm |= (1u << h);
                else          fb |= (1u << h);
            }
        }
        s_colbase[tid] = cb;
        s_mask[tid]    = mm;
        s_fb[tid]      = fb;
    }
    __syncthreads();

    const float* xb0 = x + ((size_t)bn * PTS_PER_BN + (size_t)d * 704) * NCH;
    #pragma unroll
    for (int pass = 0; pass < 4; pass++) {
        int item = pass * 256 + tid;
        if (item >= 880) break;
        int w  = item / 20;
        int c4 = item - w * 20;
        unsigned mm = s_mask[w];
        unsigned fb = s_fb[w];
        if (!(mm | fb)) continue;
        const float* xb = xb0 + (size_t)w * NCH + c4 * 4;
        float ax = 0.f, ay = 0.f, az = 0.f, aw = 0.f;
        #pragma unroll
        for (int h = 0; h < 16; h++) {
            if ((mm >> h) & 1u) {
                float4 v = *(const float4*)(xb + h * HSTRIDE);
                ax += v.x; ay += v.y; az += v.z; aw += v.w;
            } else if ((fb >> h) & 1u) {
                float4 v = *(const float4*)(xb + h * HSTRIDE);
                int vb = s_base[h * 44 + w];
                float* o = out + (size_t)(vb >> 16) * OUT_PER_B + (vb & 65535);
                atomicAdd(o + (size_t)(c4*4 + 0) * GRID_HW, v.x);
                atomicAdd(o + (size_t)(c4*4 + 1) * GRID_HW, v.y);
                atomicAdd(o + (size_t)(c4*4 + 2) * GRID_HW, v.z);
                atomicAdd(o + (size_t)(c4*4 + 3) * GRID_HW, v.w);
            }
        }
        if (mm) {
            int vb = s_colbase[w];
            float* o = out + (size_t)(vb >> 16) * OUT_PER_B + (vb & 65535);
            atomicAdd(o + (size_t)(c4*4 + 0) * GRID_HW, ax);
            atomicAdd(o + (size_t)(c4*4 + 1) * GRID_HW, ay);
            atomicAdd(o + (size_t)(c4*4 + 2) * GRID_HW, az);
            atomicAdd(o + (size_t)(c4*4 + 3) * GRID_HW, aw);
        }
    }
}

extern "C" void kernel_launch(void* const* d_in, const int* in_sizes, int n_in,
                              void* d_out, int out_size, void* d_ws, size_t ws_size,
                              hipStream_t stream) {
    const float* x          = (const float*)d_in[0];
    const float* rots       = (const float*)d_in[1];
    const float* trans      = (const float*)d_in[2];
    const float* intrins    = (const float*)d_in[3];
    const float* post_rots  = (const float*)d_in[4];
    const float* post_trans = (const float*)d_in[5];
    float* out = (float*)d_out;

    if (ws_size >= (size_t)WS_NEED) {
        float* P       = (float*)d_ws;
        int*   nxt     = (int*)((char*)d_ws + NEXT_OFF);
        int*   head    = (int*)((char*)d_ws + HEAD_OFF);
        int*   counter = (int*)((char*)d_ws + CNT_OFF);
        init_heads<<<512, 256, 0, stream>>>(head, counter);
        scatter_compact<<<576, 256, 0, stream>>>(x, rots, trans, intrins,
                                                 post_rots, post_trans,
                                                 P, nxt, head, counter);
        gather_kernel<<<2048, 256, 0, stream>>>(P, nxt, head, out);
    } else if (ws_size >= 12 * 24 * sizeof(double)) {
        double* tw = (double*)d_ws;
        zero_kernel<<<2560, 256, 0, stream>>>((float4*)out, out_size / 16);
        prep_kernel<<<1, 64, 0, stream>>>(rots, trans, intrins, post_rots, post_trans, tw);
        scatter_direct_kernel<<<576, 256, 0, stream>>>(x, tw, out);
    }
}

// Round 2
// 240.375 us; speedup vs baseline: 1.0422x; 1.0422x over previous
//
#include <hip/hip_runtime.h>

// LSS voxel pooling: B=2,N=6,D=48,FH=16,FW=44,C=80 -> out [2,80,1,256,256]
//
// R7: harness poisons ws with TWO 519MB fills per timed iteration (~152us
// fixed tax; _ord 19/21 adjacency in R5 profile). Our kernels ~= 98us, of
// which the fused scatter is ~65 (unchanged R4-R6 -- every prior edit moved
// the flush side, not slice processing). Scatter is latency-bound: 2.25
// waves/SIMD + per-h branchy loads. Fix: split into
//   geom_groups (576 blk, f64 geometry + group build + list link, ~5us)
//   reduce      (2048 blk grid-stride, no LDS/barriers, branchless
//                unconditional 16x float4 loads masked by fmaf -> P)
//   gather      (list walk -> dense out, heads staged in LDS)
// Predicted: reduce ~20us @ >=4.5TB/s, total 250 -> ~205.
//
// Numerics (verified R1-R6, absmax 0.016): f64 geometry seeded with bit-exact
// f32 frustum values + f32-valued bounds constants; trunc-toward-zero.

#define NCH       80
#define GRID_HW   65536    // 256*256
#define OUT_PER_B 5242880  // 80*65536
#define HSTRIDE   3520     // 44*80 floats between h rows
#define PTS_PER_BN 33792   // 48*16*44

// workspace layout (bytes)
#define N_ENT_MAX 405504           // 576 slices * 44 cols * 16 groups worst case
#define P_BYTES   129761280u       // N_ENT_MAX * 80 * 4
#define NEXT_OFF  129761280u       // N_ENT_MAX * 4 = 1622016
#define HEAD_OFF  131383296u       // 131072 * 4   = 524288
#define CNT_OFF   131907584u       // 4 (padded to 256)
#define META_OFF  131907840u       // N_ENT_MAX * 4 = 1622016
#define WS_NEED   133529856u

__device__ inline void inv3(const double a[9], double inv[9]) {
    double c00 =  a[4]*a[8] - a[5]*a[7];
    double c01 = -(a[3]*a[8] - a[5]*a[6]);
    double c02 =  a[3]*a[7] - a[4]*a[6];
    double det = a[0]*c00 + a[1]*c01 + a[2]*c02;
    double id  = 1.0/det;
    inv[0] = c00*id;
    inv[1] = (a[2]*a[7]-a[1]*a[8])*id;
    inv[2] = (a[1]*a[5]-a[2]*a[4])*id;
    inv[3] = c01*id;
    inv[4] = (a[0]*a[8]-a[2]*a[6])*id;
    inv[5] = (a[2]*a[3]-a[0]*a[5])*id;
    inv[6] = c02*id;
    inv[7] = (a[1]*a[6]-a[0]*a[7])*id;
    inv[8] = (a[0]*a[4]-a[1]*a[3])*id;
}

// o[0..8]=inv(post_rots), [9..17]=rots@inv(intrins), [18..20]=post_trans, [21..23]=trans
__device__ inline void prep_bn(const float* __restrict__ rots,
                               const float* __restrict__ trans,
                               const float* __restrict__ intrins,
                               const float* __restrict__ post_rots,
                               const float* __restrict__ post_trans,
                               int bn, double* o) {
    double pr[9], kk[9], rt[9], ipr[9], ik[9];
    #pragma unroll
    for (int i = 0; i < 9; i++) {
        pr[i] = (double)post_rots[bn*9 + i];
        kk[i] = (double)intrins[bn*9 + i];
        rt[i] = (double)rots[bn*9 + i];
    }
    inv3(pr, ipr);
    inv3(kk, ik);
    #pragma unroll
    for (int i = 0; i < 9; i++) o[i] = ipr[i];
    #pragma unroll
    for (int r = 0; r < 3; r++)
        #pragma unroll
        for (int c = 0; c < 3; c++)
            o[9 + r*3 + c] = rt[r*3+0]*ik[0*3+c] + rt[r*3+1]*ik[1*3+c] + rt[r*3+2]*ik[2*3+c];
    #pragma unroll
    for (int i = 0; i < 3; i++) o[18 + i] = (double)post_trans[bn*3 + i];
    #pragma unroll
    for (int i = 0; i < 3; i++) o[21 + i] = (double)trans[bn*3 + i];
}

// fallback-path prep kernel (writes tw[bn*24..])
__global__ void prep_kernel(const float* __restrict__ rots,
                            const float* __restrict__ trans,
                            const float* __restrict__ intrins,
                            const float* __restrict__ post_rots,
                            const float* __restrict__ post_trans,
                            double* __restrict__ tw) {
    int bn = threadIdx.x;
    if (bn >= 12) return;
    prep_bn(rots, trans, intrins, post_rots, post_trans, bn, tw + bn*24);
}

__global__ __launch_bounds__(256) void zero_kernel(float4* __restrict__ p, int n4) {
    int i = blockIdx.x * 256 + threadIdx.x;
    int stride = gridDim.x * 256;
    for (; i < n4; i += stride) p[i] = make_float4(0.f, 0.f, 0.f, 0.f);
}

__global__ __launch_bounds__(256) void init_heads(int* __restrict__ head, int* __restrict__ counter) {
    int i = blockIdx.x * 256 + threadIdx.x;
    if (i < 131072) head[i] = -1;
    if (i == 0) counter[0] = 0;
}

// ---- shared geometry: fills s_base (vox id = b*65536+gy*256+gx, or -1). ----
__device__ inline void geom_points(const double* __restrict__ t,
                                   int b, int d, int tid, int* s_base) {
    const float dsv = __fadd_rn(2.0f, __fmul_rn((float)(56.0 / 48.0), (float)d));
    for (int idx = tid; idx < 704; idx += 256) {
        const int h = idx / 44;
        const int w = idx - h * 44;
        float xsv = (w == 43) ? 703.0f : (float)((double)w * (703.0 / 43.0));
        float ysv = (float)(h * 17);

        double px = (double)xsv - t[18];
        double py = (double)ysv - t[19];
        double pz = (double)dsv - t[20];
        double q0 = t[0]*px + t[1]*py + t[2]*pz;
        double q1 = t[3]*px + t[4]*py + t[5]*pz;
        double q2 = t[6]*px + t[7]*py + t[8]*pz;
        q0 *= q2;
        q1 *= q2;
        double e0 = t[9]*q0  + t[10]*q1 + t[11]*q2 + t[21];
        double e1 = t[12]*q0 + t[13]*q1 + t[14]*q2 + t[22];
        double e2 = t[15]*q0 + t[16]*q1 + t[17]*q2 + t[23];

        const double lxy = (double)(-51.2f);
        const double dxy = (double)(0.4f);
        int gx = (int)((e0 - lxy) / dxy);
        int gy = (int)((e1 - lxy) / dxy);
        int gz = (int)((e2 - (double)(-10.0f)) / (double)(20.0f));
        int base = -1;
        if (gx >= 0 && gx < 256 && gy >= 0 && gy < 256 && gz == 0)
            base = (b << 16) | (gy << 8) | gx;     // voxel id (incl. batch)
        s_base[idx] = base;
    }
}

// K1: geometry + per-column voxel-group build + list link.
// Emits per-entry packed meta: slice(10b)<<22 | w(6b)<<16 | mask(16b).
__global__ __launch_bounds__(256) void geom_groups(const float* __restrict__ rots,
                                                   const float* __restrict__ trans,
                                                   const float* __restrict__ intrins,
                                                   const float* __restrict__ post_rots,
                                                   const float* __restrict__ post_trans,
                                                   int* __restrict__ nxt,
                                                   int* __restrict__ head,
                                                   int* __restrict__ counter,
                                                   unsigned* __restrict__ ent_meta) {
    __shared__ double   s_t[24];
    __shared__ int      s_base[704];
    __shared__ int      s_gbase[704];    // [w*16+k]
    __shared__ unsigned s_gmask[704];    // [w*16+k]
    __shared__ int      s_gcount[44];
    __shared__ int      s_goff[44];
    __shared__ int      s_eb;

    const int tid   = threadIdx.x;
    const int slice = blockIdx.x;        // bn*48 + d
    const int bn    = slice / 48;
    const int d     = slice - bn * 48;
    const int b     = bn / 6;

    if (tid == 0)
        prep_bn(rots, trans, intrins, post_rots, post_trans, bn, s_t);
    __syncthreads();

    geom_points(s_t, b, d, tid, s_base);
    __syncthreads();

    // group the 16 h-rows of each column by voxel id (real data: 1 group/col)
    if (tid < 44) {
        int gb[16]; unsigned gm[16];
        int cnt = 0;
        #pragma unroll
        for (int h = 0; h < 16; h++) {
            int pb = s_base[h * 44 + tid];
            if (pb >= 0) {
                int j = 0;
                for (; j < cnt; j++) if (gb[j] == pb) break;
                if (j < cnt) gm[j] |= (1u << h);
                else { gb[cnt] = pb; gm[cnt] = (1u << h); cnt++; }
            }
        }
        s_gcount[tid] = cnt;
        for (int j = 0; j < cnt; j++) {
            s_gbase[tid * 16 + j] = gb[j];
            s_gmask[tid * 16 + j] = gm[j];
        }
    }
    __syncthreads();

    if (tid == 0) {
        int off = 0;
        for (int w = 0; w < 44; w++) { s_goff[w] = off; off += s_gcount[w]; }
        s_eb = atomicAdd(counter, off);   // reserve contiguous entry range
    }
    __syncthreads();

    if (tid < 44) {
        int off = s_goff[tid];
        int cnt = s_gcount[tid];
        for (int k = 0; k < cnt; k++) {
            int e = s_eb + off + k;
            ent_meta[e] = ((unsigned)slice << 22) | ((unsigned)tid << 16)
                        | (s_gmask[tid * 16 + k] & 0xFFFFu);
            nxt[e] = atomicExch(&head[s_gbase[tid * 16 + k]], e);
        }
    }
}

// K2: pure streaming x -> P. Grid-stride over NE*20 items; no LDS, no
// barriers; unconditional float4 loads (always in-bounds), masked via fmaf
// so all 16 loads issue back-to-back.
__global__ __launch_bounds__(256) void reduce_kernel(const float* __restrict__ x,
                                                     const unsigned* __restrict__ ent_meta,
                                                     const int* __restrict__ counter,
                                                     float* __restrict__ P) {
    const int NE = counter[0];
    const int total = NE * 20;
    int i = blockIdx.x * 256 + threadIdx.x;
    const int stride = gridDim.x * 256;
    for (; i < total; i += stride) {
        int e  = i / 20;
        int c4 = i - e * 20;
        unsigned meta = ent_meta[e];
        int slice   = (int)(meta >> 22);
        int w       = (int)((meta >> 16) & 63u);
        unsigned mm = meta & 0xFFFFu;
        const float* xb = x + (size_t)(slice * 704 + w) * NCH + c4 * 4;
        float ax = 0.f, ay = 0.f, az = 0.f, aw = 0.f;
        #pragma unroll
        for (int h = 0; h < 16; h++) {
            float4 v = *(const float4*)(xb + h * HSTRIDE);
            float m = (float)((mm >> h) & 1u);
            ax = fmaf(m, v.x, ax);
            ay = fmaf(m, v.y, ay);
            az = fmaf(m, v.z, az);
            aw = fmaf(m, v.w, aw);
        }
        float4 r; r.x = ax; r.y = ay; r.z = az; r.w = aw;
        // lanes c4-minor -> 320B contiguous per entry
        *(float4*)(P + (size_t)e * NCH + c4 * 4) = r;
    }
}

// K3: walk per-voxel lists, sum P rows, write out[b][c][v] dense (all of out).
__global__ __launch_bounds__(256) void gather_kernel(const float* __restrict__ P,
                                                     const int* __restrict__ nxt,
                                                     const int* __restrict__ head,
                                                     float* __restrict__ out) {
    __shared__ float tile[64 * 81];
    __shared__ int   s_head[64];
    const int tid = threadIdx.x;
    const int b   = blockIdx.x >> 10;
    const int v0  = (blockIdx.x & 1023) * 64;
    if (tid < 64) s_head[tid] = head[(b << 16) + v0 + tid];
    __syncthreads();
    for (int i = 0; i < 20; i++) {
        int j = i * 256 + tid;          // 0..5119
        int v = j / 80;
        int c = j - v * 80;
        float s = 0.f;
        int e = s_head[v];
        while (e >= 0) {
            s += P[(size_t)e * NCH + c];  // 320B contiguous per entry
            e = nxt[e];
        }
        tile[v * 81 + c] = s;
    }
    __syncthreads();
    float* dst = out + (size_t)b * OUT_PER_B + v0;
    #pragma unroll
    for (int i = 0; i < 20; i++) {
        int k  = i * 256 + tid;
        int c  = k >> 6;                // 0..79
        int lv = k & 63;
        dst[(size_t)c * GRID_HW + lv] = tile[lv * 81 + c];  // 256B/wave-row
    }
}

// Fallback (ws too small): direct atomics into out (R3 structure).
__global__ __launch_bounds__(256) void scatter_direct_kernel(const float* __restrict__ x,
                                                             const double* __restrict__ ws,
                                                             float* __restrict__ out) {
    __shared__ int      s_base[704];
    __shared__ int      s_colbase[44];
    __shared__ unsigned s_mask[44];
    __shared__ unsigned s_fb[44];

    const int tid = threadIdx.x;
    const int bn  = blockIdx.x / 48;
    const int d   = blockIdx.x - bn * 48;
    const int b   = bn / 6;
    geom_points(ws + bn * 24, b, d, tid, s_base);
    __syncthreads();

    if (tid < 44) {
        int cb = -1; unsigned mm = 0, fb = 0;
        #pragma unroll
        for (int h = 0; h < 16; h++) {
            int pb = s_base[h * 44 + tid];
            if (pb >= 0) {
                if (cb < 0) cb = pb;
                if (pb == cb) mm |= (1u << h);
                else          fb |= (1u << h);
            }
        }
        s_colbase[tid] = cb;
        s_mask[tid]    = mm;
        s_fb[tid]      = fb;
    }
    __syncthreads();

    const float* xb0 = x + ((size_t)bn * PTS_PER_BN + (size_t)d * 704) * NCH;
    #pragma unroll
    for (int pass = 0; pass < 4; pass++) {
        int item = pass * 256 + tid;
        if (item >= 880) break;
        int w  = item / 20;
        int c4 = item - w * 20;
        unsigned mm = s_mask[w];
        unsigned fb = s_fb[w];
        if (!(mm | fb)) continue;
        const float* xb = xb0 + (size_t)w * NCH + c4 * 4;
        float ax = 0.f, ay = 0.f, az = 0.f, aw = 0.f;
        #pragma unroll
        for (int h = 0; h < 16; h++) {
            if ((mm >> h) & 1u) {
                float4 v = *(const float4*)(xb + h * HSTRIDE);
                ax += v.x; ay += v.y; az += v.z; aw += v.w;
            } else if ((fb >> h) & 1u) {
                float4 v = *(const float4*)(xb + h * HSTRIDE);
                int vb = s_base[h * 44 + w];
                float* o = out + (size_t)(vb >> 16) * OUT_PER_B + (vb & 65535);
                atomicAdd(o + (size_t)(c4*4 + 0) * GRID_HW, v.x);
                atomicAdd(o + (size_t)(c4*4 + 1) * GRID_HW, v.y);
                atomicAdd(o + (size_t)(c4*4 + 2) * GRID_HW, v.z);
                atomicAdd(o + (size_t)(c4*4 + 3) * GRID_HW, v.w);
            }
        }
        if (mm) {
            int vb = s_colbase[w];
            float* o = out + (size_t)(vb >> 16) * OUT_PER_B + (vb & 65535);
            atomicAdd(o + (size_t)(c4*4 + 0) * GRID_HW, ax);
            atomicAdd(o + (size_t)(c4*4 + 1) * GRID_HW, ay);
            atomicAdd(o + (size_t)(c4*4 + 2) * GRID_HW, az);
            atomicAdd(o + (size_t)(c4*4 + 3) * GRID_HW, aw);
        }
    }
}

extern "C" void kernel_launch(void* const* d_in, const int* in_sizes, int n_in,
                              void* d_out, int out_size, void* d_ws, size_t ws_size,
                              hipStream_t stream) {
    const float* x          = (const float*)d_in[0];
    const float* rots       = (const float*)d_in[1];
    const float* trans      = (const float*)d_in[2];
    const float* intrins    = (const float*)d_in[3];
    const float* post_rots  = (const float*)d_in[4];
    const float* post_trans = (const float*)d_in[5];
    float* out = (float*)d_out;

    if (ws_size >= (size_t)WS_NEED) {
        float*    P       = (float*)d_ws;
        int*      nxt     = (int*)((char*)d_ws + NEXT_OFF);
        int*      head    = (int*)((char*)d_ws + HEAD_OFF);
        int*      counter = (int*)((char*)d_ws + CNT_OFF);
        unsigned* meta    = (unsigned*)((char*)d_ws + META_OFF);
        init_heads<<<512, 256, 0, stream>>>(head, counter);
        geom_groups<<<576, 256, 0, stream>>>(rots, trans, intrins,
                                             post_rots, post_trans,
                                             nxt, head, counter, meta);
        reduce_kernel<<<2048, 256, 0, stream>>>(x, meta, counter, P);
        gather_kernel<<<2048, 256, 0, stream>>>(P, nxt, head, out);
    } else if (ws_size >= 12 * 24 * sizeof(double)) {
        double* tw = (double*)d_ws;
        zero_kernel<<<2560, 256, 0, stream>>>((float4*)out, out_size / 16);
        prep_kernel<<<1, 64, 0, stream>>>(rots, trans, intrins, post_rots, post_trans, tw);
        scatter_direct_kernel<<<576, 256, 0, stream>>>(x, tw, out);
    }
}